// Round 4
// baseline (433.024 us; speedup 1.0000x reference)
//
#include <hip/hip_runtime.h>
#include <hip/hip_bf16.h>
#include <math.h>
#include <stdint.h>

#define NBR 8
#define SDIM 64
#define DDIM 1024
#define BROWS 16384
#define CAP 16384

// ---------------- threefry2x32, key = (0, 1234), JAX-exact ----------------
__device__ __forceinline__ void tf2x32(uint32_t& x0, uint32_t& x1) {
  const uint32_t k0 = 0u, k1 = 1234u;
  const uint32_t ks2 = k0 ^ k1 ^ 0x1BD11BDAu;
#define TFR(r) { x0 += x1; x1 = (x1 << (r)) | (x1 >> (32 - (r))); x1 ^= x0; }
  x0 += k0; x1 += k1;
  TFR(13) TFR(15) TFR(26) TFR(6)
  x0 += k1;  x1 += ks2 + 1u;
  TFR(17) TFR(29) TFR(16) TFR(24)
  x0 += ks2; x1 += k0 + 2u;
  TFR(13) TFR(15) TFR(26) TFR(6)
  x0 += k0;  x1 += k1 + 3u;
  TFR(17) TFR(29) TFR(16) TFR(24)
  x0 += k1;  x1 += ks2 + 4u;
  TFR(13) TFR(15) TFR(26) TFR(6)
  x0 += ks2; x1 += k0 + 5u;
#undef TFR
}

// ---------------- K1: fold v[n][d] = sum_s W_in[n][d][s]*W_sw[n][s] (fp64) ----
__global__ __launch_bounds__(256) void k_fold(
    const float* __restrict__ W_in, const float* __restrict__ b_in,
    const float* __restrict__ W_sw, const float* __restrict__ b_sw,
    double* __restrict__ v, double* __restrict__ c, int* __restrict__ count) {
  int gid = blockIdx.x * 256 + threadIdx.x;
  if (gid < NBR * DDIM) {
    int n = gid >> 10, d = gid & 1023;
    const float* wi = W_in + ((size_t)n * DDIM + d) * SDIM;
    const float* ws = W_sw + n * SDIM;
    double acc = 0.0;
    for (int s = 0; s < SDIM; s++) acc += (double)wi[s] * (double)ws[s];
    v[gid] = acc;
  } else if (gid < NBR * DDIM + NBR) {
    int n = gid - NBR * DDIM;
    const float* bi = b_in + n * SDIM;
    const float* ws = W_sw + n * SDIM;
    double acc = (double)b_sw[n];
    for (int s = 0; s < SDIM; s++) acc += (double)bi[s] * (double)ws[s];
    c[n] = acc;
  } else if (gid < NBR * DDIM + 2 * NBR) {
    count[gid - NBR * DDIM - NBR] = 0;
  }
}

// ---------------- K2: logits (fp64) + gumbel (partitionable threefry) -------
// one wave per row; grid 1024 x 256 (4096 waves, 4 rows each)
__global__ __launch_bounds__(256) void k_logits(
    const float* __restrict__ x, const double* __restrict__ vg,
    const double* __restrict__ cg_, float* __restrict__ out_logits,
    float* __restrict__ out_index, float* __restrict__ out_hard,
    float* __restrict__ gate, int* __restrict__ count, int* __restrict__ order) {
  __shared__ double vs[NBR][DDIM];   // exactly 64 KiB
  int t = threadIdx.x;
  for (int i = t; i < NBR * DDIM / 2; i += 256)
    ((double2*)vs)[i] = ((const double2*)vg)[i];
  __syncthreads();
  int wid = t >> 6, l = t & 63;
  double cn = cg_[l & 7];
  int gw = blockIdx.x * 4 + wid;
  for (int row = gw; row < BROWS; row += 4096) {
    const float* xr = x + (size_t)row * DDIM;
    float4 xv[4];
#pragma unroll
    for (int j = 0; j < 4; j++) {
      float4 tmp = ((const float4*)xr)[j * 64 + l];
      tmp.x = fmaxf(tmp.x, 0.f); tmp.y = fmaxf(tmp.y, 0.f);
      tmp.z = fmaxf(tmp.z, 0.f); tmp.w = fmaxf(tmp.w, 0.f);
      xv[j] = tmp;
    }
    double acc[NBR];
#pragma unroll
    for (int nn = 0; nn < NBR; nn++) {
      double a = 0.0;
#pragma unroll
      for (int j = 0; j < 4; j++) {
        const double* vv = &vs[nn][j * 256 + l * 4];
        a += (double)xv[j].x * vv[0];
        a += (double)xv[j].y * vv[1];
        a += (double)xv[j].z * vv[2];
        a += (double)xv[j].w * vv[3];
      }
      acc[nn] = a;
    }
#pragma unroll
    for (int nn = 0; nn < NBR; nn++) {
      double a = acc[nn];
#pragma unroll
      for (int off = 32; off > 0; off >>= 1) a += __shfl_xor(a, off);
      acc[nn] = a;
    }
    int n = l & 7;
    double lg = acc[0];
#pragma unroll
    for (int i = 1; i < 8; i++) lg = (n == i) ? acc[i] : lg;
    lg += cn;
    // gumbel noise — PARTITIONABLE threefry path (jax>=0.4.30 default):
    // per-element counter (hi, lo) = (0, flat_idx); 32-bit bits = w0 ^ w1;
    // u = bitcast((bits>>9)|0x3F800000) - 1 (fp32, bit-exact with ref)
    uint32_t f = (uint32_t)row * 8u + (uint32_t)n;
    uint32_t a0 = 0u, a1 = f;
    tf2x32(a0, a1);
    uint32_t bits = a0 ^ a1;
    float u = __uint_as_float(0x3F800000u | (bits >> 9)) - 1.0f;
    float ef = (float)(-log1p(-(double)u));     // exponential sample, fp32-rounded
    double gn = -log((double)ef + 1e-20);       // gumbel, fp64 downstream
    double gv = lg + gn;                        // TAU = 1
    double g[8];
#pragma unroll
    for (int i = 0; i < 8; i++) g[i] = __shfl(gv, i);
    // softmax (fp64) then first-max argmax on y_soft
    double m = g[0];
#pragma unroll
    for (int i = 1; i < 8; i++) m = fmax(m, g[i]);
    double ex[8], s = 0.0;
#pragma unroll
    for (int i = 0; i < 8; i++) { ex[i] = exp(g[i] - m); s += ex[i]; }
    int best = 0; double bv = ex[0] / s;
#pragma unroll
    for (int i = 1; i < 8; i++) {
      double ys = ex[i] / s;
      if (ys > bv) { bv = ys; best = i; }
    }
    if (l < 8) out_logits[(size_t)row * 8 + n] = (float)lg;
    if (l == 0) {
      out_index[row] = (float)best;
      double yh = (1.0 - bv) + bv;             // one_hot - y_soft + y_soft at sel
      #pragma unroll
      for (int i = 0; i < 8; i++)
        out_hard[(size_t)row * 8 + i] = (i == best) ? (float)yh : 0.0f;
      gate[row] = (float)yh;
      int pos = atomicAdd(&count[best], 1);
      if (pos < CAP) order[best * CAP + pos] = row;
    }
  }
}

// ---------------- K3: selected-branch h then out, branch-grouped rows -------
// grid 8*256 blocks of 256 threads; block = 64 rows of one branch
__global__ __launch_bounds__(256) void k_out(
    const float* __restrict__ x, const float* __restrict__ W_in,
    const float* __restrict__ b_in, const float* __restrict__ W_out,
    const float* __restrict__ b_out, const float* __restrict__ gate,
    const int* __restrict__ count, const int* __restrict__ order,
    float* __restrict__ out) {
  __shared__ int rows[64];
  __shared__ float bufA[64 * 68];   // Xt (phase1) then h (phase2), padded
  __shared__ float bufB[64 * 132];  // Wt 64x68 (phase1) / WoT 64x132 (phase2)
  int t = threadIdx.x;
  int n = blockIdx.x >> 8;
  int seg = blockIdx.x & 255;
  int cnt = count[n];
  int base = seg * 64;
  if (base >= cnt) return;
  if (t < 64) {
    int idx = base + t;
    rows[t] = (idx < cnt) ? order[n * CAP + idx] : -1;
  }
  __syncthreads();
  int cg = t & 7, rg = t >> 3;   // rows {rg, rg+32}, cols cg*8..cg*8+7
  float acc0[8] = {0,0,0,0,0,0,0,0}, acc1[8] = {0,0,0,0,0,0,0,0};
  const float* Wn = W_in + (size_t)n * DDIM * SDIM;
  int lr = t >> 2, lq = t & 3;   // loader mapping
  for (int kt = 0; kt < DDIM; kt += 64) {
    // stage X (relu) and W_in k-slab
    {
      int grow = rows[lr];
#pragma unroll
      for (int j = 0; j < 4; j++) {
        float4 tmp = make_float4(0.f, 0.f, 0.f, 0.f);
        if (grow >= 0)
          tmp = *(const float4*)&x[(size_t)grow * DDIM + kt + lq * 16 + j * 4];
        tmp.x = fmaxf(tmp.x, 0.f); tmp.y = fmaxf(tmp.y, 0.f);
        tmp.z = fmaxf(tmp.z, 0.f); tmp.w = fmaxf(tmp.w, 0.f);
        *(float4*)&bufA[lr * 68 + lq * 16 + j * 4] = tmp;
      }
#pragma unroll
      for (int j = 0; j < 4; j++) {
        float4 w = *(const float4*)&Wn[(size_t)(kt + lr) * SDIM + lq * 16 + j * 4];
        *(float4*)&bufB[lr * 68 + lq * 16 + j * 4] = w;
      }
    }
    __syncthreads();
#pragma unroll
    for (int kk = 0; kk < 64; kk += 4) {
      float4 xa = *(const float4*)&bufA[rg * 68 + kk];
      float4 xb = *(const float4*)&bufA[(rg + 32) * 68 + kk];
      const float* xap = (const float*)&xa;
      const float* xbp = (const float*)&xb;
#pragma unroll
      for (int q = 0; q < 4; q++) {
        float4 w0 = *(const float4*)&bufB[(kk + q) * 68 + cg * 8];
        float4 w1 = *(const float4*)&bufB[(kk + q) * 68 + cg * 8 + 4];
        float xs0 = xap[q], xs1 = xbp[q];
        acc0[0] = fmaf(xs0, w0.x, acc0[0]); acc0[1] = fmaf(xs0, w0.y, acc0[1]);
        acc0[2] = fmaf(xs0, w0.z, acc0[2]); acc0[3] = fmaf(xs0, w0.w, acc0[3]);
        acc0[4] = fmaf(xs0, w1.x, acc0[4]); acc0[5] = fmaf(xs0, w1.y, acc0[5]);
        acc0[6] = fmaf(xs0, w1.z, acc0[6]); acc0[7] = fmaf(xs0, w1.w, acc0[7]);
        acc1[0] = fmaf(xs1, w0.x, acc1[0]); acc1[1] = fmaf(xs1, w0.y, acc1[1]);
        acc1[2] = fmaf(xs1, w0.z, acc1[2]); acc1[3] = fmaf(xs1, w0.w, acc1[3]);
        acc1[4] = fmaf(xs1, w1.x, acc1[4]); acc1[5] = fmaf(xs1, w1.y, acc1[5]);
        acc1[6] = fmaf(xs1, w1.z, acc1[6]); acc1[7] = fmaf(xs1, w1.w, acc1[7]);
      }
    }
    __syncthreads();
  }
  // h = acc + b_in  -> bufA
  {
    const float* bi = b_in + n * SDIM + cg * 8;
#pragma unroll
    for (int i = 0; i < 8; i++) {
      float b = bi[i];
      bufA[rg * 68 + cg * 8 + i] = acc0[i] + b;
      bufA[(rg + 32) * 68 + cg * 8 + i] = acc1[i] + b;
    }
  }
  __syncthreads();
  int grow0 = rows[rg], grow1 = rows[rg + 32];
  float grt0 = (grow0 >= 0) ? gate[grow0] : 0.f;
  float grt1 = (grow1 >= 0) ? gate[grow1] : 0.f;
  // phase 2: out = x + (h @ W_out + b_out) * gate, 128-col chunks
  for (int cc = 0; cc < DDIM; cc += 128) {
    {
      int s = t >> 2, q = t & 3;
#pragma unroll
      for (int j = 0; j < 8; j++) {
        float4 w = *(const float4*)&W_out[((size_t)n * SDIM + s) * DDIM + cc + q * 32 + j * 4];
        *(float4*)&bufB[s * 132 + q * 32 + j * 4] = w;
      }
    }
    __syncthreads();
    float a20[16] = {0,0,0,0,0,0,0,0,0,0,0,0,0,0,0,0};
    float a21[16] = {0,0,0,0,0,0,0,0,0,0,0,0,0,0,0,0};
    for (int s = 0; s < 64; s++) {
      float h0 = bufA[rg * 68 + s];
      float h1 = bufA[(rg + 32) * 68 + s];
#pragma unroll
      for (int jj = 0; jj < 4; jj++) {
        float4 w = *(const float4*)&bufB[s * 132 + cg * 16 + jj * 4];
        a20[jj*4+0] = fmaf(h0, w.x, a20[jj*4+0]);
        a20[jj*4+1] = fmaf(h0, w.y, a20[jj*4+1]);
        a20[jj*4+2] = fmaf(h0, w.z, a20[jj*4+2]);
        a20[jj*4+3] = fmaf(h0, w.w, a20[jj*4+3]);
        a21[jj*4+0] = fmaf(h1, w.x, a21[jj*4+0]);
        a21[jj*4+1] = fmaf(h1, w.y, a21[jj*4+1]);
        a21[jj*4+2] = fmaf(h1, w.z, a21[jj*4+2]);
        a21[jj*4+3] = fmaf(h1, w.w, a21[jj*4+3]);
      }
    }
    const float* bp = b_out + n * DDIM + cc + cg * 16;
    if (grow0 >= 0) {
      const float* xp = x + (size_t)grow0 * DDIM + cc + cg * 16;
      float* op = out + (size_t)grow0 * DDIM + cc + cg * 16;
#pragma unroll
      for (int jj = 0; jj < 4; jj++) {
        float4 xx = *(const float4*)&xp[jj * 4];
        float4 bo = *(const float4*)&bp[jj * 4];
        float4 o;
        o.x = xx.x + (a20[jj*4+0] + bo.x) * grt0;
        o.y = xx.y + (a20[jj*4+1] + bo.y) * grt0;
        o.z = xx.z + (a20[jj*4+2] + bo.z) * grt0;
        o.w = xx.w + (a20[jj*4+3] + bo.w) * grt0;
        *(float4*)&op[jj * 4] = o;
      }
    }
    if (grow1 >= 0) {
      const float* xp = x + (size_t)grow1 * DDIM + cc + cg * 16;
      float* op = out + (size_t)grow1 * DDIM + cc + cg * 16;
#pragma unroll
      for (int jj = 0; jj < 4; jj++) {
        float4 xx = *(const float4*)&xp[jj * 4];
        float4 bo = *(const float4*)&bp[jj * 4];
        float4 o;
        o.x = xx.x + (a21[jj*4+0] + bo.x) * grt1;
        o.y = xx.y + (a21[jj*4+1] + bo.y) * grt1;
        o.z = xx.z + (a21[jj*4+2] + bo.z) * grt1;
        o.w = xx.w + (a21[jj*4+3] + bo.w) * grt1;
        *(float4*)&op[jj * 4] = o;
      }
    }
    __syncthreads();
  }
}

extern "C" void kernel_launch(void* const* d_in, const int* in_sizes, int n_in,
                              void* d_out, int out_size, void* d_ws, size_t ws_size,
                              hipStream_t stream) {
  const float* x    = (const float*)d_in[0];
  const float* W_in = (const float*)d_in[1];
  const float* b_in = (const float*)d_in[2];
  const float* W_sw = (const float*)d_in[3];
  const float* b_sw = (const float*)d_in[4];
  const float* W_out= (const float*)d_in[5];
  const float* b_out= (const float*)d_in[6];
  float* out0  = (float*)d_out;
  float* ylog  = out0 + (size_t)BROWS * DDIM;              // 16777216
  float* yidx  = ylog + (size_t)BROWS * NBR;               // +131072
  float* yhard = yidx + (size_t)BROWS;                     // +16384
  char* ws = (char*)d_ws;
  double* v   = (double*)ws;                               // 65536 B
  double* c   = (double*)(ws + 65536);                     // 64 B
  float* gate = (float*)(ws + 65600);                      // 65536 B
  int* count  = (int*)(ws + 131136);                       // 32 B
  int* order  = (int*)(ws + 131168);                       // 8*16384*4 B
  hipLaunchKernelGGL(k_fold, dim3(33), dim3(256), 0, stream,
                     W_in, b_in, W_sw, b_sw, v, c, count);
  hipLaunchKernelGGL(k_logits, dim3(1024), dim3(256), 0, stream,
                     x, v, c, ylog, yidx, yhard, gate, count, order);
  hipLaunchKernelGGL(k_out, dim3(8 * 256), dim3(256), 0, stream,
                     x, W_in, b_in, W_out, b_out, gate, count, order, out0);
}

// Round 5
// 343.581 us; speedup vs baseline: 1.2603x; 1.2603x over previous
//
#include <hip/hip_runtime.h>
#include <hip/hip_bf16.h>
#include <math.h>
#include <stdint.h>

#define NBR 8
#define SDIM 64
#define DDIM 1024
#define BROWS 16384
#define CAP 16384

typedef __attribute__((ext_vector_type(8))) short bf16x8;
typedef __attribute__((ext_vector_type(4))) float f32x4;

__device__ __forceinline__ ushort f2b(float f) {
  union { __hip_bfloat16 h; ushort u; } cv;
  cv.h = __float2bfloat16(f);
  return cv.u;
}

// ---------------- threefry2x32, key = (0, 1234), JAX-exact ----------------
__device__ __forceinline__ void tf2x32(uint32_t& x0, uint32_t& x1) {
  const uint32_t k0 = 0u, k1 = 1234u;
  const uint32_t ks2 = k0 ^ k1 ^ 0x1BD11BDAu;
#define TFR(r) { x0 += x1; x1 = (x1 << (r)) | (x1 >> (32 - (r))); x1 ^= x0; }
  x0 += k0; x1 += k1;
  TFR(13) TFR(15) TFR(26) TFR(6)
  x0 += k1;  x1 += ks2 + 1u;
  TFR(17) TFR(29) TFR(16) TFR(24)
  x0 += ks2; x1 += k0 + 2u;
  TFR(13) TFR(15) TFR(26) TFR(6)
  x0 += k0;  x1 += k1 + 3u;
  TFR(17) TFR(29) TFR(16) TFR(24)
  x0 += k1;  x1 += ks2 + 4u;
  TFR(13) TFR(15) TFR(26) TFR(6)
  x0 += ks2; x1 += k0 + 5u;
#undef TFR
}

// ---------------- K1: fold v[n][d] = sum_s W_in[n][d][s]*W_sw[n][s] (fp64) ----
__global__ __launch_bounds__(256) void k_fold(
    const float* __restrict__ W_in, const float* __restrict__ b_in,
    const float* __restrict__ W_sw, const float* __restrict__ b_sw,
    double* __restrict__ v, double* __restrict__ c, int* __restrict__ count) {
  int gid = blockIdx.x * 256 + threadIdx.x;
  if (gid < NBR * DDIM) {
    int n = gid >> 10, d = gid & 1023;
    const float* wi = W_in + ((size_t)n * DDIM + d) * SDIM;
    const float* ws = W_sw + n * SDIM;
    double acc = 0.0;
    for (int s = 0; s < SDIM; s++) acc += (double)wi[s] * (double)ws[s];
    v[gid] = acc;
  } else if (gid < NBR * DDIM + NBR) {
    int n = gid - NBR * DDIM;
    const float* bi = b_in + n * SDIM;
    const float* ws = W_sw + n * SDIM;
    double acc = (double)b_sw[n];
    for (int s = 0; s < SDIM; s++) acc += (double)bi[s] * (double)ws[s];
    c[n] = acc;
  } else if (gid < NBR * DDIM + 2 * NBR) {
    count[gid - NBR * DDIM - NBR] = 0;
  }
}

// ---------------- K2: logits (fp64) + gumbel + argmax (no softmax needed) ---
// softmax is monotone -> argmax(y_soft) == argmax(g); y_hard == exact one-hot;
// gate == 1.0 exactly. One wave per row; grid 1024 x 256.
__global__ __launch_bounds__(256) void k_logits(
    const float* __restrict__ x, const double* __restrict__ vg,
    const double* __restrict__ cg_, float* __restrict__ out_logits,
    float* __restrict__ out_index, float* __restrict__ out_hard,
    int* __restrict__ count, int* __restrict__ order) {
  __shared__ double vs[NBR][DDIM];   // exactly 64 KiB
  int t = threadIdx.x;
  for (int i = t; i < NBR * DDIM / 2; i += 256)
    ((double2*)vs)[i] = ((const double2*)vg)[i];
  __syncthreads();
  int wid = t >> 6, l = t & 63;
  double cn = cg_[l & 7];
  int gw = blockIdx.x * 4 + wid;
  for (int row = gw; row < BROWS; row += 4096) {
    const float* xr = x + (size_t)row * DDIM;
    float4 xv[4];
#pragma unroll
    for (int j = 0; j < 4; j++) {
      float4 tmp = ((const float4*)xr)[j * 64 + l];
      tmp.x = fmaxf(tmp.x, 0.f); tmp.y = fmaxf(tmp.y, 0.f);
      tmp.z = fmaxf(tmp.z, 0.f); tmp.w = fmaxf(tmp.w, 0.f);
      xv[j] = tmp;
    }
    double acc[NBR];
#pragma unroll
    for (int nn = 0; nn < NBR; nn++) {
      double a = 0.0;
#pragma unroll
      for (int j = 0; j < 4; j++) {
        const double* vv = &vs[nn][j * 256 + l * 4];
        a += (double)xv[j].x * vv[0];
        a += (double)xv[j].y * vv[1];
        a += (double)xv[j].z * vv[2];
        a += (double)xv[j].w * vv[3];
      }
      acc[nn] = a;
    }
#pragma unroll
    for (int nn = 0; nn < NBR; nn++) {
      double a = acc[nn];
#pragma unroll
      for (int off = 32; off > 0; off >>= 1) a += __shfl_xor(a, off);
      acc[nn] = a;
    }
    int n = l & 7;
    double lg = acc[0];
#pragma unroll
    for (int i = 1; i < 8; i++) lg = (n == i) ? acc[i] : lg;
    lg += cn;
    // gumbel noise — partitionable threefry (bit-exact, round-4-verified)
    uint32_t f = (uint32_t)row * 8u + (uint32_t)n;
    uint32_t a0 = 0u, a1 = f;
    tf2x32(a0, a1);
    uint32_t bits = a0 ^ a1;
    float u = __uint_as_float(0x3F800000u | (bits >> 9)) - 1.0f;
    float ef = (float)(-log1p(-(double)u));     // fp32-rounded exponential
    double gn = -log((double)ef + 1e-20);       // fp64 gumbel
    double gv = lg + gn;                        // TAU = 1
    double g[8];
#pragma unroll
    for (int i = 0; i < 8; i++) g[i] = __shfl(gv, i);
    double m = g[0]; int best = 0;
#pragma unroll
    for (int i = 1; i < 8; i++) if (g[i] > m) { m = g[i]; best = i; }
    if (l < 8) out_logits[(size_t)row * 8 + n] = (float)lg;
    if (l == 0) {
      out_index[row] = (float)best;
#pragma unroll
      for (int i = 0; i < 8; i++)
        out_hard[(size_t)row * 8 + i] = (i == best) ? 1.0f : 0.0f;
      int pos = atomicAdd(&count[best], 1);
      if (pos < CAP) order[best * CAP + pos] = row;
    }
  }
}

// ---------------- K3: MFMA bf16, selected branch, 64 rows/block --------------
// grid 8*256, 256 threads (4 waves). Phase 1: h=relu(x)@W_in (M64,N64,K1024).
// Phase 2: out = x + h@W_out + b_out (M64,N1024,K64). XOR-swizzled LDS.
__global__ __launch_bounds__(256) void k_out(
    const float* __restrict__ x, const float* __restrict__ W_in,
    const float* __restrict__ b_in, const float* __restrict__ W_out,
    const float* __restrict__ b_out, const int* __restrict__ count,
    const int* __restrict__ order, float* __restrict__ out) {
  __shared__ int rows[64];
  __shared__ __align__(16) ushort A_lds[64 * 128];   // [row][k]  16 KB
  __shared__ __align__(16) ushort Bi_lds[64 * 128];  // [col][k]  16 KB (W_in^T)
  __shared__ __align__(16) ushort H_lds[64 * 64];    // [row][s]   8 KB
  __shared__ __align__(16) ushort Bo_lds[128 * 64];  // [col][s]  16 KB (W_out^T)
  int t = threadIdx.x;
  int n = blockIdx.x >> 8;
  int seg = blockIdx.x & 255;
  int cnt = count[n];
  int base = seg * 64;
  if (base >= cnt) return;
  if (t < 64) rows[t] = (base + t < cnt) ? order[n * CAP + base + t] : -1;
  __syncthreads();
  const int l = t & 63, w = t >> 6;
  const int fr = l & 15, fg = l >> 4;     // fragment row/col index, k-group
  const int sr = t & 63, sq = t >> 6;     // stage row (or col), k-quarter
  const int aswz = (fr & 7) << 4;
  const int arow = w * 16 + fr;
  const float* Wn = W_in + (size_t)n * DDIM * SDIM;
  int grow_s = rows[sr];
  bool live = grow_s >= 0;
  const float* xsrc = x + (size_t)(live ? grow_s : 0) * DDIM;

  f32x4 acc1[4] = {};
  for (int kt = 0; kt < DDIM; kt += 128) {
    {  // stage A: relu(x) rows -> bf16, swizzled
      ushort ub[32];
#pragma unroll
      for (int j = 0; j < 8; j++) {
        float4 v = *(const float4*)&xsrc[kt + sq * 32 + j * 4];
        ub[j*4+0] = live ? f2b(fmaxf(v.x, 0.f)) : (ushort)0;
        ub[j*4+1] = live ? f2b(fmaxf(v.y, 0.f)) : (ushort)0;
        ub[j*4+2] = live ? f2b(fmaxf(v.z, 0.f)) : (ushort)0;
        ub[j*4+3] = live ? f2b(fmaxf(v.w, 0.f)) : (ushort)0;
      }
#pragma unroll
      for (int jj = 0; jj < 4; jj++) {
        int byte = sr * 256 + ((sq * 64 + jj * 16) ^ ((sr & 7) << 4));
        *(bf16x8*)((char*)A_lds + byte) = *(bf16x8*)&ub[jj * 8];
      }
    }
    {  // stage B: W_in slab transposed (coalesced read along cols)
      ushort ub[32];
#pragma unroll
      for (int j = 0; j < 32; j++)
        ub[j] = f2b(Wn[(size_t)(kt + sq * 32 + j) * SDIM + sr]);
#pragma unroll
      for (int jj = 0; jj < 4; jj++) {
        int byte = sr * 256 + ((sq * 64 + jj * 16) ^ ((sr & 7) << 4));
        *(bf16x8*)((char*)Bi_lds + byte) = *(bf16x8*)&ub[jj * 8];
      }
    }
    __syncthreads();
#pragma unroll
    for (int ks = 0; ks < 4; ks++) {
      bf16x8 af = *(const bf16x8*)((const char*)A_lds +
                    arow * 256 + ((ks * 64 + fg * 16) ^ aswz));
#pragma unroll
      for (int nt = 0; nt < 4; nt++) {
        bf16x8 bf = *(const bf16x8*)((const char*)Bi_lds +
                      (nt * 16 + fr) * 256 + ((ks * 64 + fg * 16) ^ aswz));
        acc1[nt] = __builtin_amdgcn_mfma_f32_16x16x32_bf16(af, bf, acc1[nt], 0, 0, 0);
      }
    }
    __syncthreads();
  }
  {  // h = acc1 + b_in -> H_lds (bf16, swizzled); wave writes/reads own rows
    const float* bi = b_in + n * SDIM;
#pragma unroll
    for (int nt = 0; nt < 4; nt++) {
      int col = nt * 16 + fr;
      float bb = bi[col];
#pragma unroll
      for (int r = 0; r < 4; r++) {
        int row = w * 16 + fg * 4 + r;
        int byte = row * 128 + ((col * 2) ^ ((row & 7) << 4));
        *(ushort*)((char*)H_lds + byte) = f2b(acc1[nt][r] + bb);
      }
    }
  }
  // phase 2
  const float* Wo = W_out + (size_t)n * SDIM * DDIM;
  const float* bo = b_out + n * DDIM;
  const int scol = t & 127, sh = t >> 7;
  const int hrow = w * 16 + fr;
  for (int c = 0; c < DDIM; c += 128) {
    __syncthreads();
    {  // stage W_out chunk transposed
      ushort ub[32];
#pragma unroll
      for (int j = 0; j < 32; j++)
        ub[j] = f2b(Wo[(size_t)(sh * 32 + j) * DDIM + c + scol]);
#pragma unroll
      for (int jj = 0; jj < 4; jj++) {
        int byte = scol * 128 + ((sh * 64 + jj * 16) ^ ((scol & 7) << 4));
        *(bf16x8*)((char*)Bo_lds + byte) = *(bf16x8*)&ub[jj * 8];
      }
    }
    __syncthreads();
    f32x4 acc2[8] = {};
#pragma unroll
    for (int ks = 0; ks < 2; ks++) {
      bf16x8 af = *(const bf16x8*)((const char*)H_lds +
                    hrow * 128 + ((ks * 64 + fg * 16) ^ aswz));
#pragma unroll
      for (int nt = 0; nt < 8; nt++) {
        bf16x8 bf = *(const bf16x8*)((const char*)Bo_lds +
                      (nt * 16 + fr) * 128 + ((ks * 64 + fg * 16) ^ aswz));
        acc2[nt] = __builtin_amdgcn_mfma_f32_16x16x32_bf16(af, bf, acc2[nt], 0, 0, 0);
      }
    }
#pragma unroll
    for (int nt = 0; nt < 8; nt++) {
      int col = c + nt * 16 + fr;
      float bov = bo[col];
#pragma unroll
      for (int r = 0; r < 4; r++) {
        int rloc = w * 16 + fg * 4 + r;
        int grow = rows[rloc];
        if (grow >= 0) {
          size_t off = (size_t)grow * DDIM + col;
          out[off] = x[off] + (acc2[nt][r] + bov);   // gate == 1.0 exactly
        }
      }
    }
  }
}

extern "C" void kernel_launch(void* const* d_in, const int* in_sizes, int n_in,
                              void* d_out, int out_size, void* d_ws, size_t ws_size,
                              hipStream_t stream) {
  const float* x    = (const float*)d_in[0];
  const float* W_in = (const float*)d_in[1];
  const float* b_in = (const float*)d_in[2];
  const float* W_sw = (const float*)d_in[3];
  const float* b_sw = (const float*)d_in[4];
  const float* W_out= (const float*)d_in[5];
  const float* b_out= (const float*)d_in[6];
  float* out0  = (float*)d_out;
  float* ylog  = out0 + (size_t)BROWS * DDIM;
  float* yidx  = ylog + (size_t)BROWS * NBR;
  float* yhard = yidx + (size_t)BROWS;
  char* ws = (char*)d_ws;
  double* v   = (double*)ws;                               // 65536 B
  double* c   = (double*)(ws + 65536);                     // 64 B
  int* count  = (int*)(ws + 65600);                        // 32 B
  int* order  = (int*)(ws + 65664);                        // 8*16384*4 B
  hipLaunchKernelGGL(k_fold, dim3(33), dim3(256), 0, stream,
                     W_in, b_in, W_sw, b_sw, v, c, count);
  hipLaunchKernelGGL(k_logits, dim3(1024), dim3(256), 0, stream,
                     x, v, c, ylog, yidx, yhard, count, order);
  hipLaunchKernelGGL(k_out, dim3(8 * 256), dim3(256), 0, stream,
                     x, W_in, b_in, W_out, b_out, count, order, out0);
}